// Round 7
// baseline (513.453 us; speedup 1.0000x reference)
//
#include <hip/hip_runtime.h>
#include <math.h>

// ---------------------------------------------------------------------------
// HybridBinaryClassifier360: conv1(3->6,5x5,s2,p1)+relu+maxpool2s1 ->
// conv2(6->15,3x3,s2,p1)+relu+maxpool2s1 -> fc 55815->120->84->1 ->
// RBF kernel vs 10 supports -> sigmoid -> [p, 1-p].  B=128, fp32.
//
// R16: (1) conv1 pinned to 7 waves/EU -- a 3-reg squeeze (73 budget vs 76
// natural), NOT the infeasible 12+ squeezes that collapsed R10/R13. 7
// blocks/CU -> 1792 resident, tail 256 (was 512 at 6/CU). Tripwire: VGPR=32
// or FETCH>>77MB = cliff -> revert. (2) fc1 T14 async-STAGE: issue step
// s+1's global loads (float4 A + 4 scalar B) after the RAW barrier, compute
// step s (512 FMA ~ 1024cyc covers ~900cyc latency), WAR barrier, ds_write.
// conv2/reduce/head unchanged from R15.
// ---------------------------------------------------------------------------

#define BATCH 128
#define KPAD 55816              // act row stride (floats); 16B-aligned rows

// ---------------- Kernel 1: conv1 + relu + maxpool(2,s1) -------------------
// (R14 kernel, verified 92.6us; only change: waves/EU pin 7)
#define C1_ST 78
#define C1_COLS 69
#define C1_ROWS 67
#define C1_TOT (C1_ROWS * C1_COLS)   // 4623
__global__ __launch_bounds__(256, 7) void conv1_pool_kernel(
    const float* __restrict__ x, const float* __restrict__ w,
    const float* __restrict__ bias, float* __restrict__ out) {
  const int b = blockIdx.z;
  const int P0 = blockIdx.x * 32;    // first pooled col
  const int R0 = blockIdx.y * 31;    // first pooled row
  const int tid = threadIdx.x;
  const int t = tid >> 3;            // rowgroup 0..31 (conv row R0+t)
  const int s = tid & 7;             // strip 0..7 (4 pooled cols)

  __shared__ float lds[C1_ROWS * C1_ST];   // 5226 floats = 20904 B
  float* cbuf = lds;                 // exchange reuses [0,720) after compute

  float acc[5][6];                   // conv row R0+t x 5 conv cols x 6 oc
#pragma unroll
  for (int oc = 0; oc < 6; oc++) {
    float bv = bias[oc];
#pragma unroll
    for (int dc = 0; dc < 5; dc++) acc[dc][oc] = bv;
  }

  const int ihb = 2 * R0 - 1, iwb = 2 * P0 - 1;

#pragma unroll 1
  for (int ci = 0; ci < 3; ci++) {
    __syncthreads();                 // WAR: previous ci's compute done
    const float* src = x + (size_t)(b * 3 + ci) * 62500;
#pragma unroll 1
    for (int base = tid; base < C1_TOT; base += 1024) {
      float vv[4];
      int lrv[4], ilv[4];
#pragma unroll
      for (int k = 0; k < 4; k++) {
        int i = base + (k << 8);
        int lr = (int)(((unsigned)i * 121575u) >> 23);  // i / 69
        int il = i - lr * 69;                           // i % 69
        lrv[k] = lr; ilv[k] = il;
        int ih = ihb + lr, iw = iwb + il;
        bool ok = (i < C1_TOT) && ((unsigned)ih < 250u) && ((unsigned)iw < 250u);
        vv[k] = ok ? src[ih * 250 + iw] : 0.f;
      }
#pragma unroll
      for (int k = 0; k < 4; k++) {
        int i = base + (k << 8);
        if (i < C1_TOT) lds[lrv[k] * C1_ST + ilv[k] + (ilv[k] >> 3)] = vv[k];
      }
    }
    __syncthreads();                 // RAW: staging visible

    const float* rbase = &lds[(2 * t) * C1_ST + 9 * s];
#pragma unroll
    for (int ir = 0; ir < 5; ir++) {
      const float* rpl = rbase + ir * C1_ST;
      const float* rph = rpl + 1;
      float v[13];
#pragma unroll
      for (int j = 0; j < 8; j++)  v[j] = rpl[j];
#pragma unroll
      for (int j = 8; j < 13; j++) v[j] = rph[j];
#pragma unroll
      for (int oc = 0; oc < 6; oc++) {
        const float* wr = w + ((oc * 3 + ci) * 5 + ir) * 5;
        float w0 = wr[0], w1 = wr[1], w2 = wr[2], w3 = wr[3], w4 = wr[4];
#pragma unroll
        for (int dc = 0; dc < 5; dc++) {
          float a = acc[dc][oc];
          a += w0 * v[2 * dc + 0];
          a += w1 * v[2 * dc + 1];
          a += w2 * v[2 * dc + 2];
          a += w3 * v[2 * dc + 3];
          a += w4 * v[2 * dc + 4];
          acc[dc][oc] = a;
        }
      }
    }
  }

  // ---- wave-boundary exchange: conv rows 8/16/24 publish for t=7/15/23 ----
  __syncthreads();                   // all compute done; input slice dead
  if (t == 8 || t == 16 || t == 24) {
    float* cb = &cbuf[(((t >> 3) - 1) * 8 + s) * 30];
#pragma unroll
    for (int oc = 0; oc < 6; oc++)
#pragma unroll
      for (int dc = 0; dc < 5; dc++) cb[oc * 5 + dc] = acc[dc][oc];
  }
  __syncthreads();                   // cbuf visible

  const int p0 = R0 + t;
  const int c0 = P0 + 4 * s;
  const bool edge = ((t & 7) == 7) && (t < 31);   // neighbor is cross-wave
  const bool wr_ok = (t < 31) && (p0 < 123);
  const float* cb = &cbuf[((t >> 3) * 8 + s) * 30];

#pragma unroll
  for (int oc = 0; oc < 6; oc++) {
    float a0 = acc[0][oc], a1 = acc[1][oc], a2 = acc[2][oc],
          a3 = acc[3][oc], a4 = acc[4][oc];
    float n0 = __shfl_down(a0, 8), n1 = __shfl_down(a1, 8),
          n2 = __shfl_down(a2, 8), n3 = __shfl_down(a3, 8),
          n4 = __shfl_down(a4, 8);
    if (edge) {
      n0 = cb[oc * 5 + 0]; n1 = cb[oc * 5 + 1]; n2 = cb[oc * 5 + 2];
      n3 = cb[oc * 5 + 3]; n4 = cb[oc * 5 + 4];
    }
    if (wr_ok) {
      float* orow = out + ((size_t)(b * 6 + oc) * 123 + p0) * 123;
      float m0 = fmaxf(fmaxf(fmaxf(a0, a1), fmaxf(n0, n1)), 0.f);
      float m1 = fmaxf(fmaxf(fmaxf(a1, a2), fmaxf(n1, n2)), 0.f);
      float m2 = fmaxf(fmaxf(fmaxf(a2, a3), fmaxf(n2, n3)), 0.f);
      float m3 = fmaxf(fmaxf(fmaxf(a3, a4), fmaxf(n3, n4)), 0.f);
      if (c0 + 3 < 123) {
        *(float4*)&orow[c0] = make_float4(m0, m1, m2, m3);
      } else {
        if (c0 < 123) orow[c0] = m0;
        if (c0 + 1 < 123) orow[c0 + 1] = m1;
        if (c0 + 2 < 123) orow[c0 + 2] = m2;
      }
    }
  }
}

// ---------------- Kernel 2: conv2 + relu + maxpool(2,s1) -------------------
// pool1 [128,6,123,123] -> act [128][KPAD] (k = oc*3721 + r*61 + c, padded)
// (unchanged from R15)
#define C2_ST 84
#define C2_TOT (35 * 67)    // 2345
__global__ __launch_bounds__(256) void conv2_pool_kernel(
    const float* __restrict__ in, const float* __restrict__ w,
    const float* __restrict__ bias, float* __restrict__ out) {
  const int b = blockIdx.z;
  const int P0 = blockIdx.x * 32;
  const int R0 = blockIdx.y * 16;
  const int tid = threadIdx.x;
  const int t = tid >> 4;           // pooled row 0..15
  const int s = tid & 15;           // strip 0..15 (2 pooled cols)

  __shared__ float lds[35 * C2_ST];

  const int ihb = 2 * R0 - 1, iwb = 2 * P0 - 1;
  const int r = R0 + t;
  const int c0 = P0 + 2 * s;

  float acc0[3][15], acc1[3][15];   // conv rows r, r+1 x 3 conv cols x 15 oc
#pragma unroll
  for (int oc = 0; oc < 15; oc++) {
    float bv = bias[oc];
#pragma unroll
    for (int dc = 0; dc < 3; dc++) { acc0[dc][oc] = bv; acc1[dc][oc] = bv; }
  }

#pragma unroll 1
  for (int ci = 0; ci < 6; ci++) {
    __syncthreads();               // WAR
    const float* src = in + (size_t)(b * 6 + ci) * 15129;  // 123*123
#pragma unroll 1
    for (int base = tid; base < C2_TOT; base += 1024) {
      float vv[4];
      int ladr[4];
#pragma unroll
      for (int k = 0; k < 4; k++) {
        int i = base + (k << 8);
        int lr = (int)(((unsigned)i * 125204u) >> 23);  // i / 67
        int il = i - lr * 67;                           // i % 67
        int ih = ihb + lr, iw = iwb + il;
        bool ok = (i < C2_TOT) && ((unsigned)ih < 123u) && ((unsigned)iw < 123u);
        vv[k] = ok ? src[ih * 123 + iw] : 0.f;
        ladr[k] = (i < C2_TOT) ? (lr * C2_ST + il + (il >> 2)) : -1;
      }
#pragma unroll
      for (int k = 0; k < 4; k++) {
        if (ladr[k] >= 0) lds[ladr[k]] = vv[k];
      }
    }
    __syncthreads();               // RAW

#pragma unroll 1
    for (int ir = 0; ir < 5; ir++) {
      const float* rp = &lds[(2 * t + ir) * C2_ST + 5 * s];
      float v[7];
#pragma unroll
      for (int j = 0; j < 7; j++) v[j] = rp[j + (j >> 2)];

      if (ir < 3) {                // conv row r, kh = ir
#pragma unroll
        for (int oc = 0; oc < 15; oc++) {
          const float* wr = w + ((oc * 6 + ci) * 3 + ir) * 3;
          float w0 = wr[0], w1 = wr[1], w2 = wr[2];
#pragma unroll
          for (int dc = 0; dc < 3; dc++) {
            float a = acc0[dc][oc];
            a += w0 * v[2 * dc + 0];
            a += w1 * v[2 * dc + 1];
            a += w2 * v[2 * dc + 2];
            acc0[dc][oc] = a;
          }
        }
      }
      if (ir >= 2) {               // conv row r+1, kh = ir-2
#pragma unroll
        for (int oc = 0; oc < 15; oc++) {
          const float* wr = w + ((oc * 6 + ci) * 3 + (ir - 2)) * 3;
          float w0 = wr[0], w1 = wr[1], w2 = wr[2];
#pragma unroll
          for (int dc = 0; dc < 3; dc++) {
            float a = acc1[dc][oc];
            a += w0 * v[2 * dc + 0];
            a += w1 * v[2 * dc + 1];
            a += w2 * v[2 * dc + 2];
            acc1[dc][oc] = a;
          }
        }
      }
    }
  }

  if (r < 61) {
#pragma unroll
    for (int oc = 0; oc < 15; oc++) {
      float* orow = out + (size_t)b * KPAD + (oc * 3721 + r * 61);
      float m0 = fmaxf(fmaxf(fmaxf(acc0[0][oc], acc0[1][oc]),
                             fmaxf(acc1[0][oc], acc1[1][oc])), 0.f);
      float m1 = fmaxf(fmaxf(fmaxf(acc0[1][oc], acc0[2][oc]),
                             fmaxf(acc1[1][oc], acc1[2][oc])), 0.f);
      if (c0 + 1 < 61) {
        *(float2*)&orow[c0] = make_float2(m0, m1);
      } else if (c0 < 61) {
        orow[c0] = m0;
      }
    }
  }
}

// ---------------- Kernel 3: fc1 split-K GEMM partials ----------------------
// act [128][KPAD] x fc1_w [120][KTOT] -> partial [NPART][15360]
// R16: T14 async-STAGE. Step s+1's global loads (1 float4 A + 4 scalar B
// per thread) issue right after the RAW barrier; compute step s (512 FMA)
// covers the load latency; WAR barrier; ds_write. Barrier count unchanged.
#define KTOT 55815
#define NPART 512
#define KCHUNK 112
#define KSTEP 16
__global__ __launch_bounds__(512) void fc1_splitk_kernel(
    const float* __restrict__ act, const float* __restrict__ w,
    float* __restrict__ partial) {
  const int kbase = blockIdx.x * KCHUNK;
  const int tid = threadIdx.x;
  const int tx = tid & 31, ty = tid >> 5;
  __shared__ float ldsA[KSTEP * 132];
  __shared__ float ldsB[KSTEP * 132];
  float acc[8][4];
#pragma unroll
  for (int i = 0; i < 8; i++)
#pragma unroll
    for (int j = 0; j < 4; j++) acc[i][j] = 0.f;

  const int mA = tid >> 2;            // 0..127
  const int qA = (tid & 3) * 4;       // k offset within step: 0,4,8,12

  // ---- staging loader (to registers) ----
  float4 pa;
  float pb[4];
  int pbn[4], pbk[4];
#pragma unroll
  for (int j = 0; j < 4; j++) {
    int i = tid + j * 512;            // 0..2047; valid < 1920
    pbn[j] = i >> 4;                  // B row 0..119
    pbk[j] = i & 15;                  // k within step
  }

#define FC1_LOAD(S)                                                         \
  {                                                                         \
    int kofs_ = kbase + (S) * KSTEP;                                        \
    int k_ = kofs_ + qA;                                                    \
    if (k_ + 3 < KTOT) {                                                    \
      pa = *(const float4*)&act[(size_t)mA * KPAD + k_];                    \
    } else {                                                                \
      pa.x = (k_ + 0 < KTOT) ? act[(size_t)mA * KPAD + k_ + 0] : 0.f;       \
      pa.y = (k_ + 1 < KTOT) ? act[(size_t)mA * KPAD + k_ + 1] : 0.f;       \
      pa.z = (k_ + 2 < KTOT) ? act[(size_t)mA * KPAD + k_ + 2] : 0.f;       \
      pa.w = (k_ + 3 < KTOT) ? act[(size_t)mA * KPAD + k_ + 3] : 0.f;       \
    }                                                                       \
    _Pragma("unroll")                                                       \
    for (int j = 0; j < 4; j++) {                                           \
      int valid_ = (tid + j * 512) < 1920;                                  \
      int k2_ = kofs_ + pbk[j];                                             \
      pb[j] = (valid_ && k2_ < KTOT) ? w[(size_t)pbn[j] * KTOT + k2_] : 0.f;\
    }                                                                       \
  }

#define FC1_WRITE()                                                         \
  {                                                                         \
    ldsA[(qA + 0) * 132 + mA] = pa.x;                                       \
    ldsA[(qA + 1) * 132 + mA] = pa.y;                                       \
    ldsA[(qA + 2) * 132 + mA] = pa.z;                                       \
    ldsA[(qA + 3) * 132 + mA] = pa.w;                                       \
    _Pragma("unroll")                                                       \
    for (int j = 0; j < 4; j++)                                             \
      if ((tid + j * 512) < 1920) ldsB[pbk[j] * 132 + pbn[j]] = pb[j];      \
  }

  FC1_LOAD(0)
  FC1_WRITE()

#pragma unroll 1
  for (int s16 = 0; s16 < KCHUNK / KSTEP; s16++) {
    __syncthreads();                  // RAW: LDS for step s16 visible
    if (s16 + 1 < KCHUNK / KSTEP) FC1_LOAD(s16 + 1)   // overlap w/ compute
#pragma unroll
    for (int kk = 0; kk < KSTEP; kk++) {
      float4 a0 = *(const float4*)&ldsA[kk * 132 + ty * 8];
      float4 a1 = *(const float4*)&ldsA[kk * 132 + ty * 8 + 4];
      float4 b0 = *(const float4*)&ldsB[kk * 132 + tx * 4];
      float av[8] = {a0.x, a0.y, a0.z, a0.w, a1.x, a1.y, a1.z, a1.w};
      float bv[4] = {b0.x, b0.y, b0.z, b0.w};
#pragma unroll
      for (int i = 0; i < 8; i++)
#pragma unroll
        for (int j = 0; j < 4; j++) acc[i][j] += av[i] * bv[j];
    }
    if (s16 + 1 < KCHUNK / KSTEP) {
      __syncthreads();                // WAR: all done reading step s16
      FC1_WRITE()
    }
  }

  if (tx < 30) {
    float* dst = partial + (size_t)blockIdx.x * 15360;
#pragma unroll
    for (int i = 0; i < 8; i++) {
      int row = ty * 8 + i;
      float4 st = make_float4(acc[i][0], acc[i][1], acc[i][2], acc[i][3]);
      *(float4*)&dst[row * 120 + tx * 4] = st;
    }
  }
}

// ---------------- Kernel 4: fused reduce (512 partials) + bias + relu ------
// (unchanged from R15)
__global__ __launch_bounds__(256) void fc1_reduce_kernel(
    const float* __restrict__ partial, const float* __restrict__ bias,
    float* __restrict__ h1) {
  const int g = threadIdx.x >> 5, il = threadIdx.x & 31;
  const int idx = blockIdx.x * 32 + il;
  const float* p = partial + (size_t)g * 15360 + idx;
  float s = 0.f;
#pragma unroll 8
  for (int q = 0; q < 64; q++) s += p[(size_t)(q * 8) * 15360];
  __shared__ float red[8][32];
  red[g][il] = s;
  __syncthreads();
  if (threadIdx.x < 32) {
    float tsum = 0.f;
#pragma unroll
    for (int gg = 0; gg < 8; gg++) tsum += red[gg][threadIdx.x];
    h1[idx] = fmaxf(tsum + bias[idx % 120], 0.f);
  }
}

// ---------------- Kernel 5: fc2 + fc3 + RBF + sigmoid ----------------------
__global__ __launch_bounds__(128) void head_kernel(
    const float* __restrict__ h1, const float* __restrict__ fc2_w,
    const float* __restrict__ fc2_b, const float* __restrict__ fc3_w,
    const float* __restrict__ fc3_b, const float* __restrict__ support,
    float* __restrict__ out) {
  int b = blockIdx.x, t = threadIdx.x;
  __shared__ float hrow[120];
  __shared__ float s2[84];
  if (t < 120) hrow[t] = h1[b * 120 + t];
  __syncthreads();
  if (t < 84) {
    float d = fc2_b[t];
    for (int k = 0; k < 120; k++) d += fc2_w[t * 120 + k] * hrow[k];
    s2[t] = fmaxf(d, 0.f);
  }
  __syncthreads();
  if (t == 0) {
    float h = fc3_b[0];
    for (int j = 0; j < 84; j++) h += fc3_w[j] * s2[j];
    float ks = 0.f;
    for (int j = 0; j < 10; j++) {
      float diff = h - support[j];
      ks += expf(-diff * diff);
    }
    ks *= 0.1f;
    float p = 1.f / (1.f + expf(-ks));
    out[b * 2] = p;
    out[b * 2 + 1] = 1.f - p;
  }
}

// ---------------------------------------------------------------------------
extern "C" void kernel_launch(void* const* d_in, const int* in_sizes, int n_in,
                              void* d_out, int out_size, void* d_ws, size_t ws_size,
                              hipStream_t stream) {
  const float* x   = (const float*)d_in[0];
  const float* c1w = (const float*)d_in[1];
  const float* c1b = (const float*)d_in[2];
  const float* c2w = (const float*)d_in[3];
  const float* c2b = (const float*)d_in[4];
  const float* f1w = (const float*)d_in[5];
  const float* f1b = (const float*)d_in[6];
  const float* f2w = (const float*)d_in[7];
  const float* f2b = (const float*)d_in[8];
  const float* f3w = (const float*)d_in[9];
  const float* f3b = (const float*)d_in[10];
  const float* sup = (const float*)d_in[11];
  float* out = (float*)d_out;

  char* ws = (char*)d_ws;
  // Lifetimes: pool1 [0,46.5MB) dead after conv2 -> part/h1 reuse it.
  float* pool1 = (float*)ws;                     // 46,476,288 B
  float* act   = (float*)(ws + 46476288);        // 128*KPAD*4 = 28,577,792 B
  float* part  = (float*)ws;                     // 512*15360*4 = 31,457,280 B
  float* h1    = (float*)(ws + 33000000);        //     61,440 B

  conv1_pool_kernel<<<dim3(4, 4, BATCH), 256, 0, stream>>>(x, c1w, c1b, pool1);
  conv2_pool_kernel<<<dim3(2, 4, BATCH), 256, 0, stream>>>(pool1, c2w, c2b, act);
  fc1_splitk_kernel<<<NPART, 512, 0, stream>>>(act, f1w, part);
  fc1_reduce_kernel<<<480, 256, 0, stream>>>(part, f1b, h1);
  head_kernel<<<BATCH, 128, 0, stream>>>(h1, f2w, f2b, f3w, f3b, sup, out);
}

// Round 8
// 337.030 us; speedup vs baseline: 1.5235x; 1.5235x over previous
//
#include <hip/hip_runtime.h>
#include <math.h>

// ---------------------------------------------------------------------------
// HybridBinaryClassifier360: conv1(3->6,5x5,s2,p1)+relu+maxpool2s1 ->
// conv2(6->15,3x3,s2,p1)+relu+maxpool2s1 -> fc 55815->120->84->1 ->
// RBF kernel vs 10 supports -> sigmoid -> [p, 1-p].  B=128, fp32.
//
// R17: conv1 restored to R15 exactly (3rd pin attempt collapsed to VGPR=36
// + 680MB spill -> RULE: conv1 takes NO launch-bounds min-waves arg, ever).
// fc1 T14 async-STAGE reverted (+12us: reg pressure in 512-thr block).
// NEW: fc1 split-K widened -- NPART 512->704, KCHUNK 112->80 (5 x KSTEP=16,
// barriers 14->10/block). Waves 4096->5632 = 16->22/CU (machine was half
// idle during fc1). partial 43.3MB still fits pool1's dead region; h1 moved
// to +44MB; reduce regrouped 8x88. conv2/head unchanged from R15.
// ---------------------------------------------------------------------------

#define BATCH 128
#define KPAD 55816              // act row stride (floats); 16B-aligned rows

// ---------------- Kernel 1: conv1 + relu + maxpool(2,s1) -------------------
// (EXACT R15 kernel -- verified 92.6us, 76 VGPR, no spill, NO PIN)
#define C1_ST 78
#define C1_COLS 69
#define C1_ROWS 67
#define C1_TOT (C1_ROWS * C1_COLS)   // 4623
__global__ __launch_bounds__(256) void conv1_pool_kernel(
    const float* __restrict__ x, const float* __restrict__ w,
    const float* __restrict__ bias, float* __restrict__ out) {
  const int b = blockIdx.z;
  const int P0 = blockIdx.x * 32;    // first pooled col
  const int R0 = blockIdx.y * 31;    // first pooled row
  const int tid = threadIdx.x;
  const int t = tid >> 3;            // rowgroup 0..31 (conv row R0+t)
  const int s = tid & 7;             // strip 0..7 (4 pooled cols)

  __shared__ float lds[C1_ROWS * C1_ST];   // 5226 floats = 20904 B
  float* cbuf = lds;                 // exchange reuses [0,720) after compute

  float acc[5][6];                   // conv row R0+t x 5 conv cols x 6 oc
#pragma unroll
  for (int oc = 0; oc < 6; oc++) {
    float bv = bias[oc];
#pragma unroll
    for (int dc = 0; dc < 5; dc++) acc[dc][oc] = bv;
  }

  const int ihb = 2 * R0 - 1, iwb = 2 * P0 - 1;

#pragma unroll 1
  for (int ci = 0; ci < 3; ci++) {
    __syncthreads();                 // WAR: previous ci's compute done
    const float* src = x + (size_t)(b * 3 + ci) * 62500;
#pragma unroll 1
    for (int base = tid; base < C1_TOT; base += 1024) {
      float vv[4];
      int lrv[4], ilv[4];
#pragma unroll
      for (int k = 0; k < 4; k++) {
        int i = base + (k << 8);
        int lr = (int)(((unsigned)i * 121575u) >> 23);  // i / 69
        int il = i - lr * 69;                           // i % 69
        lrv[k] = lr; ilv[k] = il;
        int ih = ihb + lr, iw = iwb + il;
        bool ok = (i < C1_TOT) && ((unsigned)ih < 250u) && ((unsigned)iw < 250u);
        vv[k] = ok ? src[ih * 250 + iw] : 0.f;
      }
#pragma unroll
      for (int k = 0; k < 4; k++) {
        int i = base + (k << 8);
        if (i < C1_TOT) lds[lrv[k] * C1_ST + ilv[k] + (ilv[k] >> 3)] = vv[k];
      }
    }
    __syncthreads();                 // RAW: staging visible

    const float* rbase = &lds[(2 * t) * C1_ST + 9 * s];
#pragma unroll
    for (int ir = 0; ir < 5; ir++) {
      const float* rpl = rbase + ir * C1_ST;
      const float* rph = rpl + 1;
      float v[13];
#pragma unroll
      for (int j = 0; j < 8; j++)  v[j] = rpl[j];
#pragma unroll
      for (int j = 8; j < 13; j++) v[j] = rph[j];
#pragma unroll
      for (int oc = 0; oc < 6; oc++) {
        const float* wr = w + ((oc * 3 + ci) * 5 + ir) * 5;
        float w0 = wr[0], w1 = wr[1], w2 = wr[2], w3 = wr[3], w4 = wr[4];
#pragma unroll
        for (int dc = 0; dc < 5; dc++) {
          float a = acc[dc][oc];
          a += w0 * v[2 * dc + 0];
          a += w1 * v[2 * dc + 1];
          a += w2 * v[2 * dc + 2];
          a += w3 * v[2 * dc + 3];
          a += w4 * v[2 * dc + 4];
          acc[dc][oc] = a;
        }
      }
    }
  }

  // ---- wave-boundary exchange: conv rows 8/16/24 publish for t=7/15/23 ----
  __syncthreads();                   // all compute done; input slice dead
  if (t == 8 || t == 16 || t == 24) {
    float* cb = &cbuf[(((t >> 3) - 1) * 8 + s) * 30];
#pragma unroll
    for (int oc = 0; oc < 6; oc++)
#pragma unroll
      for (int dc = 0; dc < 5; dc++) cb[oc * 5 + dc] = acc[dc][oc];
  }
  __syncthreads();                   // cbuf visible

  const int p0 = R0 + t;
  const int c0 = P0 + 4 * s;
  const bool edge = ((t & 7) == 7) && (t < 31);   // neighbor is cross-wave
  const bool wr_ok = (t < 31) && (p0 < 123);
  const float* cb = &cbuf[((t >> 3) * 8 + s) * 30];

#pragma unroll
  for (int oc = 0; oc < 6; oc++) {
    float a0 = acc[0][oc], a1 = acc[1][oc], a2 = acc[2][oc],
          a3 = acc[3][oc], a4 = acc[4][oc];
    float n0 = __shfl_down(a0, 8), n1 = __shfl_down(a1, 8),
          n2 = __shfl_down(a2, 8), n3 = __shfl_down(a3, 8),
          n4 = __shfl_down(a4, 8);
    if (edge) {
      n0 = cb[oc * 5 + 0]; n1 = cb[oc * 5 + 1]; n2 = cb[oc * 5 + 2];
      n3 = cb[oc * 5 + 3]; n4 = cb[oc * 5 + 4];
    }
    if (wr_ok) {
      float* orow = out + ((size_t)(b * 6 + oc) * 123 + p0) * 123;
      float m0 = fmaxf(fmaxf(fmaxf(a0, a1), fmaxf(n0, n1)), 0.f);
      float m1 = fmaxf(fmaxf(fmaxf(a1, a2), fmaxf(n1, n2)), 0.f);
      float m2 = fmaxf(fmaxf(fmaxf(a2, a3), fmaxf(n2, n3)), 0.f);
      float m3 = fmaxf(fmaxf(fmaxf(a3, a4), fmaxf(n3, n4)), 0.f);
      if (c0 + 3 < 123) {
        *(float4*)&orow[c0] = make_float4(m0, m1, m2, m3);
      } else {
        if (c0 < 123) orow[c0] = m0;
        if (c0 + 1 < 123) orow[c0 + 1] = m1;
        if (c0 + 2 < 123) orow[c0 + 2] = m2;
      }
    }
  }
}

// ---------------- Kernel 2: conv2 + relu + maxpool(2,s1) -------------------
// pool1 [128,6,123,123] -> act [128][KPAD] (k = oc*3721 + r*61 + c, padded)
// (unchanged from R15)
#define C2_ST 84
#define C2_TOT (35 * 67)    // 2345
__global__ __launch_bounds__(256) void conv2_pool_kernel(
    const float* __restrict__ in, const float* __restrict__ w,
    const float* __restrict__ bias, float* __restrict__ out) {
  const int b = blockIdx.z;
  const int P0 = blockIdx.x * 32;
  const int R0 = blockIdx.y * 16;
  const int tid = threadIdx.x;
  const int t = tid >> 4;           // pooled row 0..15
  const int s = tid & 15;           // strip 0..15 (2 pooled cols)

  __shared__ float lds[35 * C2_ST];

  const int ihb = 2 * R0 - 1, iwb = 2 * P0 - 1;
  const int r = R0 + t;
  const int c0 = P0 + 2 * s;

  float acc0[3][15], acc1[3][15];   // conv rows r, r+1 x 3 conv cols x 15 oc
#pragma unroll
  for (int oc = 0; oc < 15; oc++) {
    float bv = bias[oc];
#pragma unroll
    for (int dc = 0; dc < 3; dc++) { acc0[dc][oc] = bv; acc1[dc][oc] = bv; }
  }

#pragma unroll 1
  for (int ci = 0; ci < 6; ci++) {
    __syncthreads();               // WAR
    const float* src = in + (size_t)(b * 6 + ci) * 15129;  // 123*123
#pragma unroll 1
    for (int base = tid; base < C2_TOT; base += 1024) {
      float vv[4];
      int ladr[4];
#pragma unroll
      for (int k = 0; k < 4; k++) {
        int i = base + (k << 8);
        int lr = (int)(((unsigned)i * 125204u) >> 23);  // i / 67
        int il = i - lr * 67;                           // i % 67
        int ih = ihb + lr, iw = iwb + il;
        bool ok = (i < C2_TOT) && ((unsigned)ih < 123u) && ((unsigned)iw < 123u);
        vv[k] = ok ? src[ih * 123 + iw] : 0.f;
        ladr[k] = (i < C2_TOT) ? (lr * C2_ST + il + (il >> 2)) : -1;
      }
#pragma unroll
      for (int k = 0; k < 4; k++) {
        if (ladr[k] >= 0) lds[ladr[k]] = vv[k];
      }
    }
    __syncthreads();               // RAW

#pragma unroll 1
    for (int ir = 0; ir < 5; ir++) {
      const float* rp = &lds[(2 * t + ir) * C2_ST + 5 * s];
      float v[7];
#pragma unroll
      for (int j = 0; j < 7; j++) v[j] = rp[j + (j >> 2)];

      if (ir < 3) {                // conv row r, kh = ir
#pragma unroll
        for (int oc = 0; oc < 15; oc++) {
          const float* wr = w + ((oc * 6 + ci) * 3 + ir) * 3;
          float w0 = wr[0], w1 = wr[1], w2 = wr[2];
#pragma unroll
          for (int dc = 0; dc < 3; dc++) {
            float a = acc0[dc][oc];
            a += w0 * v[2 * dc + 0];
            a += w1 * v[2 * dc + 1];
            a += w2 * v[2 * dc + 2];
            acc0[dc][oc] = a;
          }
        }
      }
      if (ir >= 2) {               // conv row r+1, kh = ir-2
#pragma unroll
        for (int oc = 0; oc < 15; oc++) {
          const float* wr = w + ((oc * 6 + ci) * 3 + (ir - 2)) * 3;
          float w0 = wr[0], w1 = wr[1], w2 = wr[2];
#pragma unroll
          for (int dc = 0; dc < 3; dc++) {
            float a = acc1[dc][oc];
            a += w0 * v[2 * dc + 0];
            a += w1 * v[2 * dc + 1];
            a += w2 * v[2 * dc + 2];
            acc1[dc][oc] = a;
          }
        }
      }
    }
  }

  if (r < 61) {
#pragma unroll
    for (int oc = 0; oc < 15; oc++) {
      float* orow = out + (size_t)b * KPAD + (oc * 3721 + r * 61);
      float m0 = fmaxf(fmaxf(fmaxf(acc0[0][oc], acc0[1][oc]),
                             fmaxf(acc1[0][oc], acc1[1][oc])), 0.f);
      float m1 = fmaxf(fmaxf(fmaxf(acc0[1][oc], acc0[2][oc]),
                             fmaxf(acc1[1][oc], acc1[2][oc])), 0.f);
      if (c0 + 1 < 61) {
        *(float2*)&orow[c0] = make_float2(m0, m1);
      } else if (c0 < 61) {
        orow[c0] = m0;
      }
    }
  }
}

// ---------------- Kernel 3: fc1 split-K GEMM partials ----------------------
// act [128][KPAD] x fc1_w [120][KTOT] -> partial [NPART][15360]
// R17: NPART 512->704, KCHUNK 112->80 (5 steps of 16; barriers 10/block).
// Waves 16->22/CU. Synchronous staging (R15 style; T14 reverted).
#define KTOT 55815
#define NPART 704
#define KCHUNK 80
#define KSTEP 16
__global__ __launch_bounds__(512) void fc1_splitk_kernel(
    const float* __restrict__ act, const float* __restrict__ w,
    float* __restrict__ partial) {
  const int kbase = blockIdx.x * KCHUNK;
  const int tid = threadIdx.x;
  const int tx = tid & 31, ty = tid >> 5;
  __shared__ float ldsA[KSTEP * 132];
  __shared__ float ldsB[KSTEP * 132];
  float acc[8][4];
#pragma unroll
  for (int i = 0; i < 8; i++)
#pragma unroll
    for (int j = 0; j < 4; j++) acc[i][j] = 0.f;

  const int mA = tid >> 2;            // 0..127
  const int qA = (tid & 3) * 4;       // k offset within step: 0,4,8,12

  for (int s16 = 0; s16 < KCHUNK / KSTEP; s16++) {
    int kofs = kbase + s16 * KSTEP;
    __syncthreads();
    { // ---- A: 128 rows x 16 k = 2048 floats = 512 aligned float4 ----
      int k = kofs + qA;
      float4 a4;
      if (k + 3 < KTOT) {
        a4 = *(const float4*)&act[(size_t)mA * KPAD + k];
      } else {
        a4.x = (k + 0 < KTOT) ? act[(size_t)mA * KPAD + k + 0] : 0.f;
        a4.y = (k + 1 < KTOT) ? act[(size_t)mA * KPAD + k + 1] : 0.f;
        a4.z = (k + 2 < KTOT) ? act[(size_t)mA * KPAD + k + 2] : 0.f;
        a4.w = (k + 3 < KTOT) ? act[(size_t)mA * KPAD + k + 3] : 0.f;
      }
      ldsA[(qA + 0) * 132 + mA] = a4.x;
      ldsA[(qA + 1) * 132 + mA] = a4.y;
      ldsA[(qA + 2) * 132 + mA] = a4.z;
      ldsA[(qA + 3) * 132 + mA] = a4.w;
    }
    // ---- B: 120 rows x 16 k = 1920 floats, scalar coalesced ----
    for (int i = tid; i < 1920; i += 512) {
      int n = i >> 4, kk = i & 15;
      int k = kofs + kk;
      ldsB[kk * 132 + n] = (k < KTOT) ? w[n * KTOT + k] : 0.f;
    }
    __syncthreads();
#pragma unroll
    for (int kk = 0; kk < KSTEP; kk++) {
      float4 a0 = *(const float4*)&ldsA[kk * 132 + ty * 8];
      float4 a1 = *(const float4*)&ldsA[kk * 132 + ty * 8 + 4];
      float4 b0 = *(const float4*)&ldsB[kk * 132 + tx * 4];
      float av[8] = {a0.x, a0.y, a0.z, a0.w, a1.x, a1.y, a1.z, a1.w};
      float bv[4] = {b0.x, b0.y, b0.z, b0.w};
#pragma unroll
      for (int i = 0; i < 8; i++)
#pragma unroll
        for (int j = 0; j < 4; j++) acc[i][j] += av[i] * bv[j];
    }
  }

  if (tx < 30) {
    float* dst = partial + (size_t)blockIdx.x * 15360;
#pragma unroll
    for (int i = 0; i < 8; i++) {
      int row = ty * 8 + i;
      float4 st = make_float4(acc[i][0], acc[i][1], acc[i][2], acc[i][3]);
      *(float4*)&dst[row * 120 + tx * 4] = st;
    }
  }
}

// ---------------- Kernel 4: fused reduce (704 partials) + bias + relu ------
// partial [704][15360] -> h1 [15360].  Block: 256 thr = 8 p-groups x 32 idx.
// Thread (g, il) sums p = g, g+8, ..., g+696 (88 terms) for idx=blk*32+il.
__global__ __launch_bounds__(256) void fc1_reduce_kernel(
    const float* __restrict__ partial, const float* __restrict__ bias,
    float* __restrict__ h1) {
  const int g = threadIdx.x >> 5, il = threadIdx.x & 31;
  const int idx = blockIdx.x * 32 + il;
  const float* p = partial + (size_t)g * 15360 + idx;
  float s = 0.f;
#pragma unroll 8
  for (int q = 0; q < 88; q++) s += p[(size_t)(q * 8) * 15360];
  __shared__ float red[8][32];
  red[g][il] = s;
  __syncthreads();
  if (threadIdx.x < 32) {
    float tsum = 0.f;
#pragma unroll
    for (int gg = 0; gg < 8; gg++) tsum += red[gg][threadIdx.x];
    h1[idx] = fmaxf(tsum + bias[idx % 120], 0.f);
  }
}

// ---------------- Kernel 5: fc2 + fc3 + RBF + sigmoid ----------------------
__global__ __launch_bounds__(128) void head_kernel(
    const float* __restrict__ h1, const float* __restrict__ fc2_w,
    const float* __restrict__ fc2_b, const float* __restrict__ fc3_w,
    const float* __restrict__ fc3_b, const float* __restrict__ support,
    float* __restrict__ out) {
  int b = blockIdx.x, t = threadIdx.x;
  __shared__ float hrow[120];
  __shared__ float s2[84];
  if (t < 120) hrow[t] = h1[b * 120 + t];
  __syncthreads();
  if (t < 84) {
    float d = fc2_b[t];
    for (int k = 0; k < 120; k++) d += fc2_w[t * 120 + k] * hrow[k];
    s2[t] = fmaxf(d, 0.f);
  }
  __syncthreads();
  if (t == 0) {
    float h = fc3_b[0];
    for (int j = 0; j < 84; j++) h += fc3_w[j] * s2[j];
    float ks = 0.f;
    for (int j = 0; j < 10; j++) {
      float diff = h - support[j];
      ks += expf(-diff * diff);
    }
    ks *= 0.1f;
    float p = 1.f / (1.f + expf(-ks));
    out[b * 2] = p;
    out[b * 2 + 1] = 1.f - p;
  }
}

// ---------------------------------------------------------------------------
extern "C" void kernel_launch(void* const* d_in, const int* in_sizes, int n_in,
                              void* d_out, int out_size, void* d_ws, size_t ws_size,
                              hipStream_t stream) {
  const float* x   = (const float*)d_in[0];
  const float* c1w = (const float*)d_in[1];
  const float* c1b = (const float*)d_in[2];
  const float* c2w = (const float*)d_in[3];
  const float* c2b = (const float*)d_in[4];
  const float* f1w = (const float*)d_in[5];
  const float* f1b = (const float*)d_in[6];
  const float* f2w = (const float*)d_in[7];
  const float* f2b = (const float*)d_in[8];
  const float* f3w = (const float*)d_in[9];
  const float* f3b = (const float*)d_in[10];
  const float* sup = (const float*)d_in[11];
  float* out = (float*)d_out;

  char* ws = (char*)d_ws;
  // Lifetimes: pool1 [0,46.5MB) dead after conv2 -> part/h1 reuse it.
  float* pool1 = (float*)ws;                     // 46,476,288 B
  float* act   = (float*)(ws + 46476288);        // 128*KPAD*4 = 28,577,792 B
  float* part  = (float*)ws;                     // 704*15360*4 = 43,253,760 B
  float* h1    = (float*)(ws + 44000000);        //     61,440 B (after part)

  conv1_pool_kernel<<<dim3(4, 4, BATCH), 256, 0, stream>>>(x, c1w, c1b, pool1);
  conv2_pool_kernel<<<dim3(2, 4, BATCH), 256, 0, stream>>>(pool1, c2w, c2b, act);
  fc1_splitk_kernel<<<NPART, 512, 0, stream>>>(act, f1w, part);
  fc1_reduce_kernel<<<480, 256, 0, stream>>>(part, f1b, h1);
  head_kernel<<<BATCH, 128, 0, stream>>>(h1, f2w, f2b, f3w, f3b, sup, out);
}

// Round 9
// 320.042 us; speedup vs baseline: 1.6043x; 1.0531x over previous
//
#include <hip/hip_runtime.h>
#include <math.h>

// ---------------------------------------------------------------------------
// HybridBinaryClassifier360: conv1(3->6,5x5,s2,p1)+relu+maxpool2s1 ->
// conv2(6->15,3x3,s2,p1)+relu+maxpool2s1 -> fc 55815->120->84->1 ->
// RBF kernel vs 10 supports -> sigmoid -> [p, 1-p].  B=128, fp32.
//
// R18: fc1/reduce reverted to R15 exactly (R17's NPART=704 widening cost
// ~10us: fc1 is staging-throughput-bound, not occupancy-bound; extra
// partial traffic only added bytes). NEW: conv2 compute-once -- each thread
// computes ONLY its own conv row (acc0, ir 0..2; LDS windows 5->3); the
// pooled partner row comes from shfl_down(16) (t+1 = 16 lanes down), LDS
// exchange for wave-boundary t=3/7/11 (published by t=4/8/12), and t=15
// keeps a private acc1 for the block-edge row (16 lanes, exec-masked).
// Per-thread FMA 4860->2430. Same trick that fixed conv1 (R9->R11).
// conv1/head unchanged from R15.
// ---------------------------------------------------------------------------

#define BATCH 128
#define KPAD 55816              // act row stride (floats); 16B-aligned rows

// ---------------- Kernel 1: conv1 + relu + maxpool(2,s1) -------------------
// (EXACT R15 kernel -- verified 92.6us, 76 VGPR, no spill, NO PIN)
#define C1_ST 78
#define C1_COLS 69
#define C1_ROWS 67
#define C1_TOT (C1_ROWS * C1_COLS)   // 4623
__global__ __launch_bounds__(256) void conv1_pool_kernel(
    const float* __restrict__ x, const float* __restrict__ w,
    const float* __restrict__ bias, float* __restrict__ out) {
  const int b = blockIdx.z;
  const int P0 = blockIdx.x * 32;    // first pooled col
  const int R0 = blockIdx.y * 31;    // first pooled row
  const int tid = threadIdx.x;
  const int t = tid >> 3;            // rowgroup 0..31 (conv row R0+t)
  const int s = tid & 7;             // strip 0..7 (4 pooled cols)

  __shared__ float lds[C1_ROWS * C1_ST];   // 5226 floats = 20904 B
  float* cbuf = lds;                 // exchange reuses [0,720) after compute

  float acc[5][6];                   // conv row R0+t x 5 conv cols x 6 oc
#pragma unroll
  for (int oc = 0; oc < 6; oc++) {
    float bv = bias[oc];
#pragma unroll
    for (int dc = 0; dc < 5; dc++) acc[dc][oc] = bv;
  }

  const int ihb = 2 * R0 - 1, iwb = 2 * P0 - 1;

#pragma unroll 1
  for (int ci = 0; ci < 3; ci++) {
    __syncthreads();                 // WAR: previous ci's compute done
    const float* src = x + (size_t)(b * 3 + ci) * 62500;
#pragma unroll 1
    for (int base = tid; base < C1_TOT; base += 1024) {
      float vv[4];
      int lrv[4], ilv[4];
#pragma unroll
      for (int k = 0; k < 4; k++) {
        int i = base + (k << 8);
        int lr = (int)(((unsigned)i * 121575u) >> 23);  // i / 69
        int il = i - lr * 69;                           // i % 69
        lrv[k] = lr; ilv[k] = il;
        int ih = ihb + lr, iw = iwb + il;
        bool ok = (i < C1_TOT) && ((unsigned)ih < 250u) && ((unsigned)iw < 250u);
        vv[k] = ok ? src[ih * 250 + iw] : 0.f;
      }
#pragma unroll
      for (int k = 0; k < 4; k++) {
        int i = base + (k << 8);
        if (i < C1_TOT) lds[lrv[k] * C1_ST + ilv[k] + (ilv[k] >> 3)] = vv[k];
      }
    }
    __syncthreads();                 // RAW: staging visible

    const float* rbase = &lds[(2 * t) * C1_ST + 9 * s];
#pragma unroll
    for (int ir = 0; ir < 5; ir++) {
      const float* rpl = rbase + ir * C1_ST;
      const float* rph = rpl + 1;
      float v[13];
#pragma unroll
      for (int j = 0; j < 8; j++)  v[j] = rpl[j];
#pragma unroll
      for (int j = 8; j < 13; j++) v[j] = rph[j];
#pragma unroll
      for (int oc = 0; oc < 6; oc++) {
        const float* wr = w + ((oc * 3 + ci) * 5 + ir) * 5;
        float w0 = wr[0], w1 = wr[1], w2 = wr[2], w3 = wr[3], w4 = wr[4];
#pragma unroll
        for (int dc = 0; dc < 5; dc++) {
          float a = acc[dc][oc];
          a += w0 * v[2 * dc + 0];
          a += w1 * v[2 * dc + 1];
          a += w2 * v[2 * dc + 2];
          a += w3 * v[2 * dc + 3];
          a += w4 * v[2 * dc + 4];
          acc[dc][oc] = a;
        }
      }
    }
  }

  // ---- wave-boundary exchange: conv rows 8/16/24 publish for t=7/15/23 ----
  __syncthreads();                   // all compute done; input slice dead
  if (t == 8 || t == 16 || t == 24) {
    float* cb = &cbuf[(((t >> 3) - 1) * 8 + s) * 30];
#pragma unroll
    for (int oc = 0; oc < 6; oc++)
#pragma unroll
      for (int dc = 0; dc < 5; dc++) cb[oc * 5 + dc] = acc[dc][oc];
  }
  __syncthreads();                   // cbuf visible

  const int p0 = R0 + t;
  const int c0 = P0 + 4 * s;
  const bool edge = ((t & 7) == 7) && (t < 31);   // neighbor is cross-wave
  const bool wr_ok = (t < 31) && (p0 < 123);
  const float* cb = &cbuf[((t >> 3) * 8 + s) * 30];

#pragma unroll
  for (int oc = 0; oc < 6; oc++) {
    float a0 = acc[0][oc], a1 = acc[1][oc], a2 = acc[2][oc],
          a3 = acc[3][oc], a4 = acc[4][oc];
    float n0 = __shfl_down(a0, 8), n1 = __shfl_down(a1, 8),
          n2 = __shfl_down(a2, 8), n3 = __shfl_down(a3, 8),
          n4 = __shfl_down(a4, 8);
    if (edge) {
      n0 = cb[oc * 5 + 0]; n1 = cb[oc * 5 + 1]; n2 = cb[oc * 5 + 2];
      n3 = cb[oc * 5 + 3]; n4 = cb[oc * 5 + 4];
    }
    if (wr_ok) {
      float* orow = out + ((size_t)(b * 6 + oc) * 123 + p0) * 123;
      float m0 = fmaxf(fmaxf(fmaxf(a0, a1), fmaxf(n0, n1)), 0.f);
      float m1 = fmaxf(fmaxf(fmaxf(a1, a2), fmaxf(n1, n2)), 0.f);
      float m2 = fmaxf(fmaxf(fmaxf(a2, a3), fmaxf(n2, n3)), 0.f);
      float m3 = fmaxf(fmaxf(fmaxf(a3, a4), fmaxf(n3, n4)), 0.f);
      if (c0 + 3 < 123) {
        *(float4*)&orow[c0] = make_float4(m0, m1, m2, m3);
      } else {
        if (c0 < 123) orow[c0] = m0;
        if (c0 + 1 < 123) orow[c0 + 1] = m1;
        if (c0 + 2 < 123) orow[c0 + 2] = m2;
      }
    }
  }
}

// ---------------- Kernel 2: conv2 + relu + maxpool(2,s1) -------------------
// pool1 [128,6,123,123] -> act [128][KPAD] (k = oc*3721 + r*61 + c, padded)
// R18 compute-once: thread t computes conv row r=R0+t only (acc0, ir 0..2);
// partner row r+1 via shfl_down(16); LDS exchange for t=3/7/11 (pub by
// t=4/8/12); t=15 computes acc1 (conv row R0+16) itself, exec-masked.
#define C2_ST 84
#define C2_TOT (35 * 67)    // 2345
__global__ __launch_bounds__(256) void conv2_pool_kernel(
    const float* __restrict__ in, const float* __restrict__ w,
    const float* __restrict__ bias, float* __restrict__ out) {
  const int b = blockIdx.z;
  const int P0 = blockIdx.x * 32;
  const int R0 = blockIdx.y * 16;
  const int tid = threadIdx.x;
  const int t = tid >> 4;           // conv/pooled row 0..15
  const int s = tid & 15;           // strip 0..15 (2 pooled cols)

  __shared__ float lds[35 * C2_ST];   // 11760 B
  float* cbuf = lds;                  // exchange reuses [0,2160) after compute

  const int ihb = 2 * R0 - 1, iwb = 2 * P0 - 1;
  const int r = R0 + t;
  const int c0 = P0 + 2 * s;

  float acc0[3][15];                // conv row r x 3 conv cols x 15 oc
  float acc1[3][15];                // conv row r+1 (live only for t==15)
#pragma unroll
  for (int oc = 0; oc < 15; oc++) {
    float bv = bias[oc];
#pragma unroll
    for (int dc = 0; dc < 3; dc++) { acc0[dc][oc] = bv; acc1[dc][oc] = bv; }
  }

#pragma unroll 1
  for (int ci = 0; ci < 6; ci++) {
    __syncthreads();               // WAR
    const float* src = in + (size_t)(b * 6 + ci) * 15129;  // 123*123
#pragma unroll 1
    for (int base = tid; base < C2_TOT; base += 1024) {
      float vv[4];
      int ladr[4];
#pragma unroll
      for (int k = 0; k < 4; k++) {
        int i = base + (k << 8);
        int lr = (int)(((unsigned)i * 125204u) >> 23);  // i / 67
        int il = i - lr * 67;                           // i % 67
        int ih = ihb + lr, iw = iwb + il;
        bool ok = (i < C2_TOT) && ((unsigned)ih < 123u) && ((unsigned)iw < 123u);
        vv[k] = ok ? src[ih * 123 + iw] : 0.f;
        ladr[k] = (i < C2_TOT) ? (lr * C2_ST + il + (il >> 2)) : -1;
      }
#pragma unroll
      for (int k = 0; k < 4; k++) {
        if (ladr[k] >= 0) lds[ladr[k]] = vv[k];
      }
    }
    __syncthreads();               // RAW

    // own conv row r: kh = ir = 0..2, input rows 2t+ir
#pragma unroll 1
    for (int ir = 0; ir < 3; ir++) {
      const float* rp = &lds[(2 * t + ir) * C2_ST + 5 * s];
      float v[7];
#pragma unroll
      for (int j = 0; j < 7; j++) v[j] = rp[j + (j >> 2)];
#pragma unroll
      for (int oc = 0; oc < 15; oc++) {
        const float* wr = w + ((oc * 6 + ci) * 3 + ir) * 3;
        float w0 = wr[0], w1 = wr[1], w2 = wr[2];
#pragma unroll
        for (int dc = 0; dc < 3; dc++) {
          float a = acc0[dc][oc];
          a += w0 * v[2 * dc + 0];
          a += w1 * v[2 * dc + 1];
          a += w2 * v[2 * dc + 2];
          acc0[dc][oc] = a;
        }
      }
    }
    // block-edge row r+1 = R0+16: only t==15 (16 lanes, exec-masked)
    if (t == 15) {
#pragma unroll 1
      for (int kh = 0; kh < 3; kh++) {
        const float* rp = &lds[(32 + kh) * C2_ST + 5 * s];
        float v[7];
#pragma unroll
        for (int j = 0; j < 7; j++) v[j] = rp[j + (j >> 2)];
#pragma unroll
        for (int oc = 0; oc < 15; oc++) {
          const float* wr = w + ((oc * 6 + ci) * 3 + kh) * 3;
          float w0 = wr[0], w1 = wr[1], w2 = wr[2];
#pragma unroll
          for (int dc = 0; dc < 3; dc++) {
            float a = acc1[dc][oc];
            a += w0 * v[2 * dc + 0];
            a += w1 * v[2 * dc + 1];
            a += w2 * v[2 * dc + 2];
            acc1[dc][oc] = a;
          }
        }
      }
    }
  }

  // ---- wave-boundary exchange: t=4/8/12 publish acc0 for t=3/7/11 ----
  __syncthreads();                   // all compute done; staging LDS dead
  if (t == 4 || t == 8 || t == 12) {
    float* cb = &cbuf[(((t >> 2) - 1) * 16 + s) * 45];
#pragma unroll
    for (int oc = 0; oc < 15; oc++)
#pragma unroll
      for (int dc = 0; dc < 3; dc++) cb[oc * 3 + dc] = acc0[dc][oc];
  }
  __syncthreads();                   // cbuf visible

  const bool edge = (t == 3 || t == 7 || t == 11);
  const float* cb = &cbuf[((t >> 2) * 16 + s) * 45];
  const bool wr_ok = (r < 61);

#pragma unroll
  for (int oc = 0; oc < 15; oc++) {
    float a0 = acc0[0][oc], a1 = acc0[1][oc], a2 = acc0[2][oc];
    // shuffles issued by ALL lanes (sources must be active)
    float n0 = __shfl_down(a0, 16), n1 = __shfl_down(a1, 16),
          n2 = __shfl_down(a2, 16);
    if (edge) {
      n0 = cb[oc * 3 + 0]; n1 = cb[oc * 3 + 1]; n2 = cb[oc * 3 + 2];
    }
    if (t == 15) {
      n0 = acc1[0][oc]; n1 = acc1[1][oc]; n2 = acc1[2][oc];
    }
    if (wr_ok) {
      float* orow = out + (size_t)b * KPAD + (oc * 3721 + r * 61);
      float m0 = fmaxf(fmaxf(fmaxf(a0, a1), fmaxf(n0, n1)), 0.f);
      float m1 = fmaxf(fmaxf(fmaxf(a1, a2), fmaxf(n1, n2)), 0.f);
      if (c0 + 1 < 61) {
        *(float2*)&orow[c0] = make_float2(m0, m1);
      } else if (c0 < 61) {
        orow[c0] = m0;
      }
    }
  }
}

// ---------------- Kernel 3: fc1 split-K GEMM partials ----------------------
// (EXACT R15 kernel: NPART=512, KCHUNK=112, KSTEP=16, float4 A staging)
#define KTOT 55815
#define NPART 512
#define KCHUNK 112
#define KSTEP 16
__global__ __launch_bounds__(512) void fc1_splitk_kernel(
    const float* __restrict__ act, const float* __restrict__ w,
    float* __restrict__ partial) {
  const int kbase = blockIdx.x * KCHUNK;
  const int tid = threadIdx.x;
  const int tx = tid & 31, ty = tid >> 5;
  __shared__ float ldsA[KSTEP * 132];
  __shared__ float ldsB[KSTEP * 132];
  float acc[8][4];
#pragma unroll
  for (int i = 0; i < 8; i++)
#pragma unroll
    for (int j = 0; j < 4; j++) acc[i][j] = 0.f;

  const int mA = tid >> 2;            // 0..127
  const int qA = (tid & 3) * 4;       // k offset within step: 0,4,8,12

  for (int s16 = 0; s16 < KCHUNK / KSTEP; s16++) {
    int kofs = kbase + s16 * KSTEP;
    __syncthreads();
    { // ---- A: 128 rows x 16 k = 2048 floats = 512 aligned float4 ----
      int k = kofs + qA;
      float4 a4;
      if (k + 3 < KTOT) {
        a4 = *(const float4*)&act[(size_t)mA * KPAD + k];
      } else {
        a4.x = (k + 0 < KTOT) ? act[(size_t)mA * KPAD + k + 0] : 0.f;
        a4.y = (k + 1 < KTOT) ? act[(size_t)mA * KPAD + k + 1] : 0.f;
        a4.z = (k + 2 < KTOT) ? act[(size_t)mA * KPAD + k + 2] : 0.f;
        a4.w = (k + 3 < KTOT) ? act[(size_t)mA * KPAD + k + 3] : 0.f;
      }
      ldsA[(qA + 0) * 132 + mA] = a4.x;
      ldsA[(qA + 1) * 132 + mA] = a4.y;
      ldsA[(qA + 2) * 132 + mA] = a4.z;
      ldsA[(qA + 3) * 132 + mA] = a4.w;
    }
    // ---- B: 120 rows x 16 k = 1920 floats, scalar coalesced ----
    for (int i = tid; i < 1920; i += 512) {
      int n = i >> 4, kk = i & 15;
      int k = kofs + kk;
      ldsB[kk * 132 + n] = (k < KTOT) ? w[n * KTOT + k] : 0.f;
    }
    __syncthreads();
#pragma unroll
    for (int kk = 0; kk < KSTEP; kk++) {
      float4 a0 = *(const float4*)&ldsA[kk * 132 + ty * 8];
      float4 a1 = *(const float4*)&ldsA[kk * 132 + ty * 8 + 4];
      float4 b0 = *(const float4*)&ldsB[kk * 132 + tx * 4];
      float av[8] = {a0.x, a0.y, a0.z, a0.w, a1.x, a1.y, a1.z, a1.w};
      float bv[4] = {b0.x, b0.y, b0.z, b0.w};
#pragma unroll
      for (int i = 0; i < 8; i++)
#pragma unroll
        for (int j = 0; j < 4; j++) acc[i][j] += av[i] * bv[j];
    }
  }

  if (tx < 30) {
    float* dst = partial + (size_t)blockIdx.x * 15360;
#pragma unroll
    for (int i = 0; i < 8; i++) {
      int row = ty * 8 + i;
      float4 st = make_float4(acc[i][0], acc[i][1], acc[i][2], acc[i][3]);
      *(float4*)&dst[row * 120 + tx * 4] = st;
    }
  }
}

// ---------------- Kernel 4: fused reduce (512 partials) + bias + relu ------
// (EXACT R15 kernel)
__global__ __launch_bounds__(256) void fc1_reduce_kernel(
    const float* __restrict__ partial, const float* __restrict__ bias,
    float* __restrict__ h1) {
  const int g = threadIdx.x >> 5, il = threadIdx.x & 31;
  const int idx = blockIdx.x * 32 + il;
  const float* p = partial + (size_t)g * 15360 + idx;
  float s = 0.f;
#pragma unroll 8
  for (int q = 0; q < 64; q++) s += p[(size_t)(q * 8) * 15360];
  __shared__ float red[8][32];
  red[g][il] = s;
  __syncthreads();
  if (threadIdx.x < 32) {
    float tsum = 0.f;
#pragma unroll
    for (int gg = 0; gg < 8; gg++) tsum += red[gg][threadIdx.x];
    h1[idx] = fmaxf(tsum + bias[idx % 120], 0.f);
  }
}

// ---------------- Kernel 5: fc2 + fc3 + RBF + sigmoid ----------------------
__global__ __launch_bounds__(128) void head_kernel(
    const float* __restrict__ h1, const float* __restrict__ fc2_w,
    const float* __restrict__ fc2_b, const float* __restrict__ fc3_w,
    const float* __restrict__ fc3_b, const float* __restrict__ support,
    float* __restrict__ out) {
  int b = blockIdx.x, t = threadIdx.x;
  __shared__ float hrow[120];
  __shared__ float s2[84];
  if (t < 120) hrow[t] = h1[b * 120 + t];
  __syncthreads();
  if (t < 84) {
    float d = fc2_b[t];
    for (int k = 0; k < 120; k++) d += fc2_w[t * 120 + k] * hrow[k];
    s2[t] = fmaxf(d, 0.f);
  }
  __syncthreads();
  if (t == 0) {
    float h = fc3_b[0];
    for (int j = 0; j < 84; j++) h += fc3_w[j] * s2[j];
    float ks = 0.f;
    for (int j = 0; j < 10; j++) {
      float diff = h - support[j];
      ks += expf(-diff * diff);
    }
    ks *= 0.1f;
    float p = 1.f / (1.f + expf(-ks));
    out[b * 2] = p;
    out[b * 2 + 1] = 1.f - p;
  }
}

// ---------------------------------------------------------------------------
extern "C" void kernel_launch(void* const* d_in, const int* in_sizes, int n_in,
                              void* d_out, int out_size, void* d_ws, size_t ws_size,
                              hipStream_t stream) {
  const float* x   = (const float*)d_in[0];
  const float* c1w = (const float*)d_in[1];
  const float* c1b = (const float*)d_in[2];
  const float* c2w = (const float*)d_in[3];
  const float* c2b = (const float*)d_in[4];
  const float* f1w = (const float*)d_in[5];
  const float* f1b = (const float*)d_in[6];
  const float* f2w = (const float*)d_in[7];
  const float* f2b = (const float*)d_in[8];
  const float* f3w = (const float*)d_in[9];
  const float* f3b = (const float*)d_in[10];
  const float* sup = (const float*)d_in[11];
  float* out = (float*)d_out;

  char* ws = (char*)d_ws;
  // Lifetimes: pool1 [0,46.5MB) dead after conv2 -> part/h1 reuse it.
  float* pool1 = (float*)ws;                     // 46,476,288 B
  float* act   = (float*)(ws + 46476288);        // 128*KPAD*4 = 28,577,792 B
  float* part  = (float*)ws;                     // 512*15360*4 = 31,457,280 B
  float* h1    = (float*)(ws + 33000000);        //     61,440 B

  conv1_pool_kernel<<<dim3(4, 4, BATCH), 256, 0, stream>>>(x, c1w, c1b, pool1);
  conv2_pool_kernel<<<dim3(2, 4, BATCH), 256, 0, stream>>>(pool1, c2w, c2b, act);
  fc1_splitk_kernel<<<NPART, 512, 0, stream>>>(act, f1w, part);
  fc1_reduce_kernel<<<480, 256, 0, stream>>>(part, f1b, h1);
  head_kernel<<<BATCH, 128, 0, stream>>>(h1, f2w, f2b, f3w, f3b, sup, out);
}